// Round 6
// baseline (482.630 us; speedup 1.0000x reference)
//
#include <hip/hip_runtime.h>
#include <hip/hip_bf16.h>

// SNU network: 4 layers, B=256, T=100, N_IN=784, N_MID=1024, N_OUT=10, tau=0.8
// Layer-batched, activations [T][B][N] (m = t*B+b) in fp8 e4m3; GEMMs use
// mfma_scale_f32_16x16x128_f8f6f4 with unit scales. Z stays bf16.
// GEMM v2: A-fragments direct from global (L2), B double-buffered in LDS,
// ONE barrier per K-tile with staging issued after the barrier (prefetch
// has a full compute phase before the next drain). Layer 4: no LDS/barriers.

#define BDIM 256
#define TT   100
#define BB   256
#define MM   25600       // B*T
#define NMID 1024
#define K1   784
#define K1P  896         // 784 padded to 7*128
#define NOUT 10
#define N4P  16          // layer-4 N padded
#define L_TAU 0.8f

typedef __attribute__((ext_vector_type(4))) int   int4x;
typedef __attribute__((ext_vector_type(8))) int   int8x;
typedef __attribute__((ext_vector_type(4))) float f32x4;

__device__ __forceinline__ void async_copy16(const void* g, void* l) {
    __builtin_amdgcn_global_load_lds(
        (const __attribute__((address_space(1))) unsigned int*)g,
        (__attribute__((address_space(3))) unsigned int*)l,
        16, 0, 0);
}

__device__ __forceinline__ unsigned short f2bf(float f) {
    __hip_bfloat16 h = __float2bfloat16(f);
    return __builtin_bit_cast(unsigned short, h);
}
__device__ __forceinline__ float bf2f(unsigned short u) {
    return __uint_as_float((unsigned)u << 16);
}

// ---- X f32 [B][T][784] -> fp8 [m=t*B+b][896] zero-padded -------------------
__global__ void convert_x(const float* __restrict__ X, unsigned char* __restrict__ XB) {
    int m = blockIdx.x;                  // t*BB + b
    int b = m & (BB - 1);
    int t = m >> 8;
    int th = threadIdx.x;
    if (th >= K1P / 4) return;           // 224 active threads
    int pk = 0;
    if (th < K1 / 4) {                   // 196 threads cover cols 0..783 exactly
        float4 v = *(const float4*)(X + ((long)b * TT + t) * K1 + th * 4);
        pk = __builtin_amdgcn_cvt_pk_fp8_f32(v.x, v.y, 0, false);
        pk = __builtin_amdgcn_cvt_pk_fp8_f32(v.z, v.w, pk, true);
    }
    *(int*)(XB + (long)m * K1P + th * 4) = pk;
}

// ---- W f32 [K,N] -> WT fp8 [N,Kpad], zero-pad k>=K -------------------------
__device__ __forceinline__ void tc_body(const float* __restrict__ W,
                                        unsigned char* __restrict__ WT,
                                        int K, int N, int Kpad,
                                        int bx, int by, int tidx) {
    __shared__ float tile[32][33];
    int k0 = bx * 32;
    int n0 = by * 32;
    int tx = tidx & 31, ty = tidx >> 5;   // 256 threads: ty=0..7
    #pragma unroll
    for (int i = 0; i < 4; ++i) {
        int k = k0 + ty + i * 8;
        tile[ty + i * 8][tx] = (k < K) ? W[(long)k * N + n0 + tx] : 0.0f;
    }
    __syncthreads();
    int nl = tidx >> 3, kq = tidx & 7;    // n-local 0..31, k-quad 0..7
    int pk = __builtin_amdgcn_cvt_pk_fp8_f32(tile[kq * 4 + 0][nl], tile[kq * 4 + 1][nl], 0, false);
    pk     = __builtin_amdgcn_cvt_pk_fp8_f32(tile[kq * 4 + 2][nl], tile[kq * 4 + 3][nl], pk, true);
    *(int*)(WT + (long)(n0 + nl) * Kpad + k0 + kq * 4) = pk;
}

__global__ void transpose_convert(const float* __restrict__ W, unsigned char* __restrict__ WT,
                                  int K, int N, int Kpad) {
    tc_body(W, WT, K, N, Kpad, blockIdx.x, blockIdx.y, threadIdx.x);
}

// W2 and W3 in one launch (blockIdx.z selects)
__global__ void transpose_convert2(const float* __restrict__ Wa, unsigned char* __restrict__ Ta,
                                   const float* __restrict__ Wb, unsigned char* __restrict__ Tb) {
    const float* W = blockIdx.z ? Wb : Wa;
    unsigned char* T = blockIdx.z ? Tb : Ta;
    tc_body(W, T, NMID, NMID, NMID, blockIdx.x, blockIdx.y, threadIdx.x);
}

// ---- W4 f32 [1024,10] -> fp8 [16][1024], zero-pad n>=10 --------------------
__global__ void convert_w4(const float* __restrict__ W4, unsigned char* __restrict__ W4T) {
    int tid = blockIdx.x * BDIM + threadIdx.x;   // n*256 + k4, 4096 total
    int n = tid >> 8;
    int k4 = (tid & 255) * 4;
    float v0 = 0, v1 = 0, v2 = 0, v3 = 0;
    if (n < NOUT) {
        v0 = W4[(k4 + 0) * NOUT + n];
        v1 = W4[(k4 + 1) * NOUT + n];
        v2 = W4[(k4 + 2) * NOUT + n];
        v3 = W4[(k4 + 3) * NOUT + n];
    }
    int pk = __builtin_amdgcn_cvt_pk_fp8_f32(v0, v1, 0, false);
    pk     = __builtin_amdgcn_cvt_pk_fp8_f32(v2, v3, pk, true);
    *(int*)(W4T + (long)n * NMID + k4) = pk;
}

// ---- GEMM: C[M,N] = A[M,K] * BT[N,K]^T, fp8 in, bf16 out -------------------
// 128x128 tile, BK=128, 4 waves of 64x64. A-frags direct from global (L2);
// B double-buffered in LDS, one barrier/tile, staging issued post-barrier.
#define BM 128
#define BN 128
#define BKB 128          // K bytes per tile
#define MSTRIPS (MM / BM)        // 200
#define NSTRIPS (NMID / BN)      // 8
__global__ __launch_bounds__(256) void gemm_fp8(
    const unsigned char* __restrict__ A,    // [M,Kp] fp8
    const unsigned char* __restrict__ BT,   // [N,Kp] fp8
    __hip_bfloat16* __restrict__ C,         // [M,N] bf16
    int Kp)
{
    __shared__ unsigned char Bs[2 * BN * BKB];  // 2 x 16 KB, XOR-chunk swizzled

    const int tid  = threadIdx.x;
    const int wave = tid >> 6;
    const int lane = tid & 63;

    // XCD swizzle: whole M-strips per XCD so all 8 N-blocks share the A strip in L2
    const int l    = blockIdx.x;
    const int xcd  = l & 7;
    const int p    = l >> 3;
    const int bm   = (xcd * (MSTRIPS / 8) + (p >> 3)) * BM;
    const int bn   = (p & 7) * BN;

    const int wr = (wave >> 1) * 64;
    const int wc = (wave & 1) * 64;

    f32x4 acc[4][4] = {};

    // B staging: LDS dest lane-linear (tid*16B); global chunk XOR-swizzled by row&7
    const int srow = tid >> 3;           // 0..31
    const int lch  = tid & 7;
    const int gch  = lch ^ (srow & 7);
    const unsigned char* Bptr = BT + (long)(bn + srow) * Kp + gch * 16;

    const int mrow = lane & 15;
    const int g    = lane >> 4;          // K-group: k = g*32 .. g*32+31

    // A row pointers (direct global reads, 32 B/lane per fragment)
    const unsigned char* Arow[4];
    #pragma unroll
    for (int i = 0; i < 4; ++i)
        Arow[i] = A + (long)(bm + wr + i * 16 + mrow) * Kp + g * 32;

    const int nt = Kp >> 7;              // 7 or 8 K-tiles

    // prologue: stage tile 0 into buffer 0
    #pragma unroll
    for (int i = 0; i < 4; ++i)
        async_copy16(Bptr + (long)(i * 32) * Kp, &Bs[(srow + i * 32) * BKB + lch * 16]);

    for (int kt = 0; kt < nt; ++kt) {
        const int k0 = kt << 7;
        const int buf = (kt & 1) * (BN * BKB);

        // A fragments for this tile (global, L2-hot after first N-block)
        int4x alo[4], ahi[4];
        #pragma unroll
        for (int i = 0; i < 4; ++i) {
            alo[i] = *(const int4x*)(Arow[i] + k0);
            ahi[i] = *(const int4x*)(Arow[i] + k0 + 16);
        }

        __syncthreads();   // drains af (needed now) + B stage (issued one tile ago)

        // B fragments from LDS (XOR-swizzled, conflict-free)
        int8x bfr[4];
        #pragma unroll
        for (int j = 0; j < 4; ++j) {
            int row = wc + j * 16 + mrow;
            int r7  = row & 7;
            int4x lo = *(const int4x*)&Bs[buf + row * BKB + ((2 * g    ) ^ r7) * 16];
            int4x hi = *(const int4x*)&Bs[buf + row * BKB + ((2 * g + 1) ^ r7) * 16];
            bfr[j][0] = lo[0]; bfr[j][1] = lo[1]; bfr[j][2] = lo[2]; bfr[j][3] = lo[3];
            bfr[j][4] = hi[0]; bfr[j][5] = hi[1]; bfr[j][6] = hi[2]; bfr[j][7] = hi[3];
        }

        // prefetch next B tile into the other buffer (drained at NEXT barrier)
        if (kt + 1 < nt) {
            const long k1 = (long)((kt + 1) << 7);
            const int nbuf = ((kt + 1) & 1) * (BN * BKB);
            #pragma unroll
            for (int i = 0; i < 4; ++i)
                async_copy16(Bptr + (long)(i * 32) * Kp + k1,
                             &Bs[nbuf + (srow + i * 32) * BKB + lch * 16]);
        }

        #pragma unroll
        for (int i = 0; i < 4; ++i) {
            int8x af;
            af[0] = alo[i][0]; af[1] = alo[i][1]; af[2] = alo[i][2]; af[3] = alo[i][3];
            af[4] = ahi[i][0]; af[5] = ahi[i][1]; af[6] = ahi[i][2]; af[7] = ahi[i][3];
            #pragma unroll
            for (int j = 0; j < 4; ++j)
                acc[i][j] = __builtin_amdgcn_mfma_scale_f32_16x16x128_f8f6f4(
                    bfr[j], af, acc[i][j],
                    0, 0,            // cbsz=fp8 e4m3, blgp=fp8 e4m3
                    0, 0x7F,         // scale src0 = 2^0
                    0, 0x7F);        // scale src1 = 2^0
        }
    }

    // epilogue: lane&15 -> m, (lane>>4)*4+reg -> n (swapped operands)
    const int nrow4 = g * 4;
    #pragma unroll
    for (int i = 0; i < 4; ++i)
        #pragma unroll
        for (int j = 0; j < 4; ++j) {
            int gm = bm + wr + i * 16 + mrow;
            int gn = bn + wc + j * 16 + nrow4;
            ushort4 pk;
            pk.x = f2bf(acc[i][j][0]);
            pk.y = f2bf(acc[i][j][1]);
            pk.z = f2bf(acc[i][j][2]);
            pk.w = f2bf(acc[i][j][3]);
            *(ushort4*)&C[(long)gm * NMID + gn] = pk;
        }
}

// ---- SNU recurrence: Z bf16 [T][B][N] -> Y fp8 [T][B][N]; thread=(b,n-pair) -
__global__ void snu_recur(const __hip_bfloat16* __restrict__ Z,
                          const float* __restrict__ bias,
                          unsigned char* __restrict__ Y) {
    int idx = blockIdx.x * BDIM + threadIdx.x;   // [0, BB*NMID/2)
    int n2 = (idx & (NMID / 2 - 1)) * 2;
    int b  = idx >> 9;
    float2 bv = *(const float2*)(bias + n2);
    float s0 = 0.0f, y0 = 0.0f, s1 = 0.0f, y1 = 0.0f;
    const long base = (long)b * NMID + n2;
    const long stride = (long)BB * NMID;
    for (int t = 0; t < TT; ++t) {
        ushort2 z2 = *(const ushort2*)(Z + base + t * stride);
        float z0 = bf2f(z2.x), z1 = bf2f(z2.y);
        s0 = fmaxf(fmaf(L_TAU * s0, 1.0f - y0, z0), 0.0f);
        y0 = 1.0f / (1.0f + __expf(-(s0 + bv.x)));
        s1 = fmaxf(fmaf(L_TAU * s1, 1.0f - y1, z1), 0.0f);
        y1 = 1.0f / (1.0f + __expf(-(s1 + bv.y)));
        int pk = __builtin_amdgcn_cvt_pk_fp8_f32(y0, y1, 0, false);
        *(unsigned short*)(Y + base + t * stride) = (unsigned short)pk;
    }
}

// ---- Layer 4 GEMM: Z4[M,16] = Y3[M,1024](fp8) * W4T[16,1024]^T (fp8) -------
// No LDS, no barriers: W4 frags (L2-hot) + A frags direct to registers,
// 8 unrolled MFMAs. 400 blocks x 64 rows (16 rows/wave). Streaming-bound.
__global__ __launch_bounds__(256) void layer4_gemm(const unsigned char* __restrict__ Y3,
                                                   const unsigned char* __restrict__ W4T,
                                                   float* __restrict__ Z4) {
    const int tid  = threadIdx.x;
    const int wave = tid >> 6;
    const int lane = tid & 63;
    const int mrow = lane & 15;
    const int g    = lane >> 4;
    const int row  = blockIdx.x * 64 + wave * 16 + mrow;
    const unsigned char* ap = Y3  + (long)row  * NMID + g * 32;
    const unsigned char* wp = W4T + (long)mrow * NMID + g * 32;
    f32x4 acc = {};
    #pragma unroll
    for (int kt = 0; kt < 8; ++kt) {
        int4x alo = *(const int4x*)(ap + kt * 128);
        int4x ahi = *(const int4x*)(ap + kt * 128 + 16);
        int4x wlo = *(const int4x*)(wp + kt * 128);
        int4x whi = *(const int4x*)(wp + kt * 128 + 16);
        int8x af, bf;
        af[0] = alo[0]; af[1] = alo[1]; af[2] = alo[2]; af[3] = alo[3];
        af[4] = ahi[0]; af[5] = ahi[1]; af[6] = ahi[2]; af[7] = ahi[3];
        bf[0] = wlo[0]; bf[1] = wlo[1]; bf[2] = wlo[2]; bf[3] = wlo[3];
        bf[4] = whi[0]; bf[5] = whi[1]; bf[6] = whi[2]; bf[7] = whi[3];
        acc = __builtin_amdgcn_mfma_scale_f32_16x16x128_f8f6f4(
            bf, af, acc, 0, 0, 0, 0x7F, 0, 0x7F);
    }
    // D: lane&15 -> m (af rows), g*4+reg -> n (bf rows)
    *(f32x4*)&Z4[(long)row * N4P + g * 4] = acc;
}

// ---- Layer 4 recurrence + m accumulation (Z4 [T*B][16] f32) ----------------
__global__ void snu4_recur(const float* __restrict__ Z4, const float* __restrict__ b4,
                           float* __restrict__ m_out) {
    int idx = blockIdx.x * BDIM + threadIdx.x;   // b*16+n, 4096 total
    int n = idx & 15;
    int b = idx >> 4;
    if (n >= NOUT) return;
    float bv = b4[n];
    float s = 0.0f, y = 0.0f, msum = 0.0f;
    for (int t = 0; t < TT; ++t) {
        float z = Z4[((long)t * BB + b) * N4P + n];   // coalesced across idx
        s = fmaxf(fmaf(L_TAU * s, 1.0f - y, z), 0.0f);
        y = 1.0f / (1.0f + __expf(-(s + bv)));
        msum += y;
    }
    m_out[b * NOUT + n] = msum;
}

// ---- loss = -mean_b log_softmax(m)[b, y[b]] --------------------------------
__global__ void loss_kernel(const float* __restrict__ m, const int* __restrict__ y,
                            float* __restrict__ out) {
    __shared__ float red[BDIM];
    int b = threadIdx.x;   // 256 threads, 1 block
    float v[NOUT];
    float mx = -1e30f;
    #pragma unroll
    for (int n = 0; n < NOUT; ++n) { v[n] = m[b * NOUT + n]; mx = fmaxf(mx, v[n]); }
    float se = 0.0f;
    #pragma unroll
    for (int n = 0; n < NOUT; ++n) se += __expf(v[n] - mx);
    float lse = mx + __logf(se);
    int lbl = y[b];
    float vy = 0.0f;
    #pragma unroll
    for (int n = 0; n < NOUT; ++n) if (n == lbl) vy = v[n];
    red[b] = -(vy - lse);
    __syncthreads();
    for (int off = 128; off; off >>= 1) {
        if (b < off) red[b] += red[b + off];
        __syncthreads();
    }
    if (b == 0) out[0] = red[0] / (float)BB;
}

extern "C" void kernel_launch(void* const* d_in, const int* in_sizes, int n_in,
                              void* d_out, int out_size, void* d_ws, size_t ws_size,
                              hipStream_t stream) {
    const float* x  = (const float*)d_in[0];
    const int*   y  = (const int*)  d_in[1];
    const float* W1 = (const float*)d_in[2];
    const float* b1 = (const float*)d_in[3];
    const float* W2 = (const float*)d_in[4];
    const float* b2 = (const float*)d_in[5];
    const float* W3 = (const float*)d_in[6];
    const float* b3 = (const float*)d_in[7];
    const float* W4 = (const float*)d_in[8];
    const float* b4 = (const float*)d_in[9];
    float* out = (float*)d_out;

    char* ws = (char*)d_ws;
    size_t off = 0;
    auto alloc = [&](size_t bytes) {
        char* p = ws + off;
        off = (off + bytes + 255) & ~(size_t)255;
        return (void*)p;
    };
    unsigned char*  XB  = (unsigned char*) alloc((size_t)MM * K1P);
    unsigned char*  W1T = (unsigned char*) alloc((size_t)NMID * K1P);
    unsigned char*  W2T = (unsigned char*) alloc((size_t)NMID * NMID);
    unsigned char*  W3T = (unsigned char*) alloc((size_t)NMID * NMID);
    unsigned char*  W4T = (unsigned char*) alloc((size_t)N4P * NMID);
    __hip_bfloat16* Z   = (__hip_bfloat16*)alloc((size_t)MM * NMID * 2);  // [T][B][N]
    unsigned char*  Ya  = (unsigned char*) alloc((size_t)MM * NMID);
    unsigned char*  Yb  = (unsigned char*) alloc((size_t)MM * NMID);
    float*          Z4  = (float*)         alloc((size_t)MM * N4P * 4);

    // prep: convert x (t-major rows) to fp8, transpose+convert weights to fp8
    convert_x<<<MM, BDIM, 0, stream>>>(x, XB);
    transpose_convert<<<dim3(K1P / 32, NMID / 32), BDIM, 0, stream>>>(W1, W1T, K1, NMID, K1P);
    transpose_convert2<<<dim3(NMID / 32, NMID / 32, 2), BDIM, 0, stream>>>(W2, W2T, W3, W3T);
    convert_w4<<<N4P * NMID / 4 / BDIM, BDIM, 0, stream>>>(W4, W4T);

    const int gblocks = MSTRIPS * NSTRIPS;        // 1600
    const int rblocks = (BB * NMID / 2) / BDIM;   // 512
    // layer 1
    gemm_fp8<<<gblocks, BDIM, 0, stream>>>(XB, W1T, Z, K1P);
    snu_recur<<<rblocks, BDIM, 0, stream>>>(Z, b1, Ya);
    // layer 2
    gemm_fp8<<<gblocks, BDIM, 0, stream>>>(Ya, W2T, Z, NMID);
    snu_recur<<<rblocks, BDIM, 0, stream>>>(Z, b2, Yb);
    // layer 3 (reuse Ya)
    gemm_fp8<<<gblocks, BDIM, 0, stream>>>(Yb, W3T, Z, NMID);
    snu_recur<<<rblocks, BDIM, 0, stream>>>(Z, b3, Ya);
    // layer 4
    layer4_gemm<<<MM / 64, BDIM, 0, stream>>>(Ya, W4T, Z4);
    snu4_recur<<<(BB * N4P) / BDIM, BDIM, 0, stream>>>(Z4, b4, out + 1);
    loss_kernel<<<1, BDIM, 0, stream>>>(out + 1, y, out);
}

// Round 7
// 366.586 us; speedup vs baseline: 1.3166x; 1.3166x over previous
//
#include <hip/hip_runtime.h>
#include <hip/hip_bf16.h>

// SNU network: 4 layers, B=256, T=100, N_IN=784, N_MID=1024, N_OUT=10, tau=0.8
// Layer-batched, activations [T][B][N] (m = t*B+b) in fp8 e4m3; GEMMs use
// mfma_scale_f32_16x16x128_f8f6f4 with unit scales. Z stays bf16.
// GEMM: R4-proven structure (A+B staged via global_load_lds, 2 barriers/tile)
// -- the A-direct-global variant (R6) regressed to latency-bound, reverted.
// Layer 4: no LDS, no barriers (streaming). snu_recur: 4x load batching.

#define BDIM 256
#define TT   100
#define BB   256
#define MM   25600       // B*T
#define NMID 1024
#define K1   784
#define K1P  896         // 784 padded to 7*128
#define NOUT 10
#define N4P  16          // layer-4 N padded
#define L_TAU 0.8f

typedef __attribute__((ext_vector_type(4))) int   int4x;
typedef __attribute__((ext_vector_type(8))) int   int8x;
typedef __attribute__((ext_vector_type(4))) float f32x4;

__device__ __forceinline__ void async_copy16(const void* g, void* l) {
    __builtin_amdgcn_global_load_lds(
        (const __attribute__((address_space(1))) unsigned int*)g,
        (__attribute__((address_space(3))) unsigned int*)l,
        16, 0, 0);
}

__device__ __forceinline__ unsigned short f2bf(float f) {
    __hip_bfloat16 h = __float2bfloat16(f);
    return __builtin_bit_cast(unsigned short, h);
}
__device__ __forceinline__ float bf2f(unsigned short u) {
    return __uint_as_float((unsigned)u << 16);
}

// ---- X f32 [B][T][784] -> fp8 [m=t*B+b][896] zero-padded -------------------
__global__ void convert_x(const float* __restrict__ X, unsigned char* __restrict__ XB) {
    int m = blockIdx.x;                  // t*BB + b
    int b = m & (BB - 1);
    int t = m >> 8;
    int th = threadIdx.x;
    if (th >= K1P / 4) return;           // 224 active threads
    int pk = 0;
    if (th < K1 / 4) {                   // 196 threads cover cols 0..783 exactly
        float4 v = *(const float4*)(X + ((long)b * TT + t) * K1 + th * 4);
        pk = __builtin_amdgcn_cvt_pk_fp8_f32(v.x, v.y, 0, false);
        pk = __builtin_amdgcn_cvt_pk_fp8_f32(v.z, v.w, pk, true);
    }
    *(int*)(XB + (long)m * K1P + th * 4) = pk;
}

// ---- W f32 [K,N] -> WT fp8 [N,Kpad], zero-pad k>=K -------------------------
__device__ __forceinline__ void tc_body(const float* __restrict__ W,
                                        unsigned char* __restrict__ WT,
                                        int K, int N, int Kpad,
                                        int bx, int by, int tidx) {
    __shared__ float tile[32][33];
    int k0 = bx * 32;
    int n0 = by * 32;
    int tx = tidx & 31, ty = tidx >> 5;   // 256 threads: ty=0..7
    #pragma unroll
    for (int i = 0; i < 4; ++i) {
        int k = k0 + ty + i * 8;
        tile[ty + i * 8][tx] = (k < K) ? W[(long)k * N + n0 + tx] : 0.0f;
    }
    __syncthreads();
    int nl = tidx >> 3, kq = tidx & 7;    // n-local 0..31, k-quad 0..7
    int pk = __builtin_amdgcn_cvt_pk_fp8_f32(tile[kq * 4 + 0][nl], tile[kq * 4 + 1][nl], 0, false);
    pk     = __builtin_amdgcn_cvt_pk_fp8_f32(tile[kq * 4 + 2][nl], tile[kq * 4 + 3][nl], pk, true);
    *(int*)(WT + (long)(n0 + nl) * Kpad + k0 + kq * 4) = pk;
}

__global__ void transpose_convert(const float* __restrict__ W, unsigned char* __restrict__ WT,
                                  int K, int N, int Kpad) {
    tc_body(W, WT, K, N, Kpad, blockIdx.x, blockIdx.y, threadIdx.x);
}

// W2 and W3 in one launch (blockIdx.z selects)
__global__ void transpose_convert2(const float* __restrict__ Wa, unsigned char* __restrict__ Ta,
                                   const float* __restrict__ Wb, unsigned char* __restrict__ Tb) {
    const float* W = blockIdx.z ? Wb : Wa;
    unsigned char* T = blockIdx.z ? Tb : Ta;
    tc_body(W, T, NMID, NMID, NMID, blockIdx.x, blockIdx.y, threadIdx.x);
}

// ---- W4 f32 [1024,10] -> fp8 [16][1024], zero-pad n>=10 --------------------
__global__ void convert_w4(const float* __restrict__ W4, unsigned char* __restrict__ W4T) {
    int tid = blockIdx.x * BDIM + threadIdx.x;   // n*256 + k4, 4096 total
    int n = tid >> 8;
    int k4 = (tid & 255) * 4;
    float v0 = 0, v1 = 0, v2 = 0, v3 = 0;
    if (n < NOUT) {
        v0 = W4[(k4 + 0) * NOUT + n];
        v1 = W4[(k4 + 1) * NOUT + n];
        v2 = W4[(k4 + 2) * NOUT + n];
        v3 = W4[(k4 + 3) * NOUT + n];
    }
    int pk = __builtin_amdgcn_cvt_pk_fp8_f32(v0, v1, 0, false);
    pk     = __builtin_amdgcn_cvt_pk_fp8_f32(v2, v3, pk, true);
    *(int*)(W4T + (long)n * NMID + k4) = pk;
}

// ---- GEMM: C[M,N] = A[M,K] * BT[N,K]^T, fp8 in, bf16 out -------------------
// 128x128 tile, BK=128 bytes, 4 waves of 64x64, 16x16x128 f8f6f4 MFMA with
// unit scales. Swapped operands -> acc reg-dim = n -> packed ushort4 stores.
// Chunk-XOR LDS swizzle (conflict-free b128); XCD-aware block swizzle.
#define BM 128
#define BN 128
#define BKB 128          // K bytes per tile
#define MSTRIPS (MM / BM)        // 200
#define NSTRIPS (NMID / BN)      // 8
__global__ __launch_bounds__(256) void gemm_fp8(
    const unsigned char* __restrict__ A,    // [M,Kp] fp8
    const unsigned char* __restrict__ BT,   // [N,Kp] fp8
    __hip_bfloat16* __restrict__ C,         // [M,N] bf16
    int Kp)
{
    __shared__ unsigned char As[BM * BKB];  // 16 KB; slot c holds global chunk c^(row&7)
    __shared__ unsigned char Bs[BN * BKB];

    const int tid  = threadIdx.x;
    const int wave = tid >> 6;
    const int lane = tid & 63;

    // XCD swizzle: whole M-strips per XCD so all 8 N-blocks share the A strip in L2
    const int l    = blockIdx.x;
    const int xcd  = l & 7;
    const int p    = l >> 3;
    const int bm   = (xcd * (MSTRIPS / 8) + (p >> 3)) * BM;
    const int bn   = (p & 7) * BN;

    const int wr = (wave >> 1) * 64;
    const int wc = (wave & 1) * 64;

    f32x4 acc[4][4] = {};

    // staging: LDS dest lane-linear (tid*16B); global chunk XOR-swizzled by row&7
    const int srow = tid >> 3;
    const int lch  = tid & 7;
    const int gch  = lch ^ (srow & 7);
    const unsigned char* Aptr = A  + (long)(bm + srow) * Kp + gch * 16;
    const unsigned char* Bptr = BT + (long)(bn + srow) * Kp + gch * 16;

    for (int k0 = 0; k0 < Kp; k0 += BKB) {
        #pragma unroll
        for (int i = 0; i < 4; ++i) {
            async_copy16(Aptr + (long)(i * 32) * Kp + k0, &As[(srow + i * 32) * BKB + lch * 16]);
            async_copy16(Bptr + (long)(i * 32) * Kp + k0, &Bs[(srow + i * 32) * BKB + lch * 16]);
        }
        __syncthreads();

        const int mrow = lane & 15;
        const int g    = lane >> 4;          // K-group: k = g*32 .. g*32+31
        int8x af[4], bfr[4];
        #pragma unroll
        for (int i = 0; i < 4; ++i) {
            int row = wr + i * 16 + mrow;
            int r7  = row & 7;
            int4x lo = *(const int4x*)&As[row * BKB + ((2 * g    ) ^ r7) * 16];
            int4x hi = *(const int4x*)&As[row * BKB + ((2 * g + 1) ^ r7) * 16];
            af[i][0] = lo[0]; af[i][1] = lo[1]; af[i][2] = lo[2]; af[i][3] = lo[3];
            af[i][4] = hi[0]; af[i][5] = hi[1]; af[i][6] = hi[2]; af[i][7] = hi[3];
        }
        #pragma unroll
        for (int j = 0; j < 4; ++j) {
            int row = wc + j * 16 + mrow;
            int r7  = row & 7;
            int4x lo = *(const int4x*)&Bs[row * BKB + ((2 * g    ) ^ r7) * 16];
            int4x hi = *(const int4x*)&Bs[row * BKB + ((2 * g + 1) ^ r7) * 16];
            bfr[j][0] = lo[0]; bfr[j][1] = lo[1]; bfr[j][2] = lo[2]; bfr[j][3] = lo[3];
            bfr[j][4] = hi[0]; bfr[j][5] = hi[1]; bfr[j][6] = hi[2]; bfr[j][7] = hi[3];
        }
        #pragma unroll
        for (int i = 0; i < 4; ++i)
            #pragma unroll
            for (int j = 0; j < 4; ++j)
                acc[i][j] = __builtin_amdgcn_mfma_scale_f32_16x16x128_f8f6f4(
                    bfr[j], af[i], acc[i][j],
                    0, 0,            // cbsz=fp8 e4m3, blgp=fp8 e4m3
                    0, 0x7F,         // scale src0 = 2^0
                    0, 0x7F);        // scale src1 = 2^0
        __syncthreads();
    }

    // epilogue: 16x16 C/D layout: lane&15 -> m, (lane>>4)*4+reg -> n (swapped ops)
    const int mcol  = lane & 15;
    const int nrow4 = (lane >> 4) * 4;
    #pragma unroll
    for (int i = 0; i < 4; ++i)
        #pragma unroll
        for (int j = 0; j < 4; ++j) {
            int gm = bm + wr + i * 16 + mcol;
            int gn = bn + wc + j * 16 + nrow4;
            ushort4 pk;
            pk.x = f2bf(acc[i][j][0]);
            pk.y = f2bf(acc[i][j][1]);
            pk.z = f2bf(acc[i][j][2]);
            pk.w = f2bf(acc[i][j][3]);
            *(ushort4*)&C[(long)gm * NMID + gn] = pk;
        }
}

// ---- SNU recurrence: Z bf16 [T][B][N] -> Y fp8 [T][B][N]; thread=(b,n-pair) -
// 4x time-batched loads: 4 independent global loads in flight per group,
// breaking the one-load-at-a-time latency serialization.
__global__ void snu_recur(const __hip_bfloat16* __restrict__ Z,
                          const float* __restrict__ bias,
                          unsigned char* __restrict__ Y) {
    int idx = blockIdx.x * BDIM + threadIdx.x;   // [0, BB*NMID/2)
    int n2 = (idx & (NMID / 2 - 1)) * 2;
    int b  = idx >> 9;
    float2 bv = *(const float2*)(bias + n2);
    float s0 = 0.0f, y0 = 0.0f, s1 = 0.0f, y1 = 0.0f;
    const long base = (long)b * NMID + n2;
    const long stride = (long)BB * NMID;
    for (int t0 = 0; t0 < TT; t0 += 4) {
        ushort2 zz[4];
        #pragma unroll
        for (int j = 0; j < 4; ++j)
            zz[j] = *(const ushort2*)(Z + base + (t0 + j) * stride);
        #pragma unroll
        for (int j = 0; j < 4; ++j) {
            float z0 = bf2f(zz[j].x), z1 = bf2f(zz[j].y);
            s0 = fmaxf(fmaf(L_TAU * s0, 1.0f - y0, z0), 0.0f);
            y0 = 1.0f / (1.0f + __expf(-(s0 + bv.x)));
            s1 = fmaxf(fmaf(L_TAU * s1, 1.0f - y1, z1), 0.0f);
            y1 = 1.0f / (1.0f + __expf(-(s1 + bv.y)));
            int pk = __builtin_amdgcn_cvt_pk_fp8_f32(y0, y1, 0, false);
            *(unsigned short*)(Y + base + (t0 + j) * stride) = (unsigned short)pk;
        }
    }
}

// ---- Layer 4 GEMM: Z4[M,16] = Y3[M,1024](fp8) * W4T[16,1024]^T (fp8) -------
// No LDS, no barriers: W4 frags (L2-hot) + A frags direct to registers,
// 8 unrolled MFMAs. 400 blocks x 64 rows (16 rows/wave). Streaming-bound.
__global__ __launch_bounds__(256) void layer4_gemm(const unsigned char* __restrict__ Y3,
                                                   const unsigned char* __restrict__ W4T,
                                                   float* __restrict__ Z4) {
    const int tid  = threadIdx.x;
    const int wave = tid >> 6;
    const int lane = tid & 63;
    const int mrow = lane & 15;
    const int g    = lane >> 4;
    const int row  = blockIdx.x * 64 + wave * 16 + mrow;
    const unsigned char* ap = Y3  + (long)row  * NMID + g * 32;
    const unsigned char* wp = W4T + (long)mrow * NMID + g * 32;
    f32x4 acc = {};
    #pragma unroll
    for (int kt = 0; kt < 8; ++kt) {
        int4x alo = *(const int4x*)(ap + kt * 128);
        int4x ahi = *(const int4x*)(ap + kt * 128 + 16);
        int4x wlo = *(const int4x*)(wp + kt * 128);
        int4x whi = *(const int4x*)(wp + kt * 128 + 16);
        int8x af, bf;
        af[0] = alo[0]; af[1] = alo[1]; af[2] = alo[2]; af[3] = alo[3];
        af[4] = ahi[0]; af[5] = ahi[1]; af[6] = ahi[2]; af[7] = ahi[3];
        bf[0] = wlo[0]; bf[1] = wlo[1]; bf[2] = wlo[2]; bf[3] = wlo[3];
        bf[4] = whi[0]; bf[5] = whi[1]; bf[6] = whi[2]; bf[7] = whi[3];
        acc = __builtin_amdgcn_mfma_scale_f32_16x16x128_f8f6f4(
            bf, af, acc, 0, 0, 0, 0x7F, 0, 0x7F);
    }
    // D: lane&15 -> m (af rows), g*4+reg -> n (bf rows)
    *(f32x4*)&Z4[(long)row * N4P + g * 4] = acc;
}

// ---- Layer 4 recurrence + m accumulation (Z4 [T*B][16] f32) ----------------
__global__ void snu4_recur(const float* __restrict__ Z4, const float* __restrict__ b4,
                           float* __restrict__ m_out) {
    int idx = blockIdx.x * BDIM + threadIdx.x;   // b*16+n, 4096 total
    int n = idx & 15;
    int b = idx >> 4;
    if (n >= NOUT) return;
    float bv = b4[n];
    float s = 0.0f, y = 0.0f, msum = 0.0f;
    for (int t0 = 0; t0 < TT; t0 += 4) {
        float z[4];
        #pragma unroll
        for (int j = 0; j < 4; ++j)
            z[j] = Z4[((long)(t0 + j) * BB + b) * N4P + n];
        #pragma unroll
        for (int j = 0; j < 4; ++j) {
            s = fmaxf(fmaf(L_TAU * s, 1.0f - y, z[j]), 0.0f);
            y = 1.0f / (1.0f + __expf(-(s + bv)));
            msum += y;
        }
    }
    m_out[b * NOUT + n] = msum;
}

// ---- loss = -mean_b log_softmax(m)[b, y[b]] --------------------------------
__global__ void loss_kernel(const float* __restrict__ m, const int* __restrict__ y,
                            float* __restrict__ out) {
    __shared__ float red[BDIM];
    int b = threadIdx.x;   // 256 threads, 1 block
    float v[NOUT];
    float mx = -1e30f;
    #pragma unroll
    for (int n = 0; n < NOUT; ++n) { v[n] = m[b * NOUT + n]; mx = fmaxf(mx, v[n]); }
    float se = 0.0f;
    #pragma unroll
    for (int n = 0; n < NOUT; ++n) se += __expf(v[n] - mx);
    float lse = mx + __logf(se);
    int lbl = y[b];
    float vy = 0.0f;
    #pragma unroll
    for (int n = 0; n < NOUT; ++n) if (n == lbl) vy = v[n];
    red[b] = -(vy - lse);
    __syncthreads();
    for (int off = 128; off; off >>= 1) {
        if (b < off) red[b] += red[b + off];
        __syncthreads();
    }
    if (b == 0) out[0] = red[0] / (float)BB;
}

extern "C" void kernel_launch(void* const* d_in, const int* in_sizes, int n_in,
                              void* d_out, int out_size, void* d_ws, size_t ws_size,
                              hipStream_t stream) {
    const float* x  = (const float*)d_in[0];
    const int*   y  = (const int*)  d_in[1];
    const float* W1 = (const float*)d_in[2];
    const float* b1 = (const float*)d_in[3];
    const float* W2 = (const float*)d_in[4];
    const float* b2 = (const float*)d_in[5];
    const float* W3 = (const float*)d_in[6];
    const float* b3 = (const float*)d_in[7];
    const float* W4 = (const float*)d_in[8];
    const float* b4 = (const float*)d_in[9];
    float* out = (float*)d_out;

    char* ws = (char*)d_ws;
    size_t off = 0;
    auto alloc = [&](size_t bytes) {
        char* p = ws + off;
        off = (off + bytes + 255) & ~(size_t)255;
        return (void*)p;
    };
    unsigned char*  XB  = (unsigned char*) alloc((size_t)MM * K1P);
    unsigned char*  W1T = (unsigned char*) alloc((size_t)NMID * K1P);
    unsigned char*  W2T = (unsigned char*) alloc((size_t)NMID * NMID);
    unsigned char*  W3T = (unsigned char*) alloc((size_t)NMID * NMID);
    unsigned char*  W4T = (unsigned char*) alloc((size_t)N4P * NMID);
    __hip_bfloat16* Z   = (__hip_bfloat16*)alloc((size_t)MM * NMID * 2);  // [T][B][N]
    unsigned char*  Ya  = (unsigned char*) alloc((size_t)MM * NMID);
    unsigned char*  Yb  = (unsigned char*) alloc((size_t)MM * NMID);
    float*          Z4  = (float*)         alloc((size_t)MM * N4P * 4);

    // prep: convert x (t-major rows) to fp8, transpose+convert weights to fp8
    convert_x<<<MM, BDIM, 0, stream>>>(x, XB);
    transpose_convert<<<dim3(K1P / 32, NMID / 32), BDIM, 0, stream>>>(W1, W1T, K1, NMID, K1P);
    transpose_convert2<<<dim3(NMID / 32, NMID / 32, 2), BDIM, 0, stream>>>(W2, W2T, W3, W3T);
    convert_w4<<<N4P * NMID / 4 / BDIM, BDIM, 0, stream>>>(W4, W4T);

    const int gblocks = MSTRIPS * NSTRIPS;        // 1600
    const int rblocks = (BB * NMID / 2) / BDIM;   // 512
    // layer 1
    gemm_fp8<<<gblocks, BDIM, 0, stream>>>(XB, W1T, Z, K1P);
    snu_recur<<<rblocks, BDIM, 0, stream>>>(Z, b1, Ya);
    // layer 2
    gemm_fp8<<<gblocks, BDIM, 0, stream>>>(Ya, W2T, Z, NMID);
    snu_recur<<<rblocks, BDIM, 0, stream>>>(Z, b2, Yb);
    // layer 3 (reuse Ya)
    gemm_fp8<<<gblocks, BDIM, 0, stream>>>(Yb, W3T, Z, NMID);
    snu_recur<<<rblocks, BDIM, 0, stream>>>(Z, b3, Ya);
    // layer 4
    layer4_gemm<<<MM / 64, BDIM, 0, stream>>>(Ya, W4T, Z4);
    snu4_recur<<<(BB * N4P) / BDIM, BDIM, 0, stream>>>(Z4, b4, out + 1);
    loss_kernel<<<1, BDIM, 0, stream>>>(out + 1, y, out);
}

// Round 8
// 358.957 us; speedup vs baseline: 1.3445x; 1.0213x over previous
//
#include <hip/hip_runtime.h>
#include <hip/hip_bf16.h>

// SNU network: 4 layers, B=256, T=100, N_IN=784, N_MID=1024, N_OUT=10, tau=0.8
// Activations b-major: row m = b*TP + t (TP=112 pad). Each fused-GEMM block
// computes a 112x128 tile = ALL t for one (b, n-block), runs the SNU
// recurrence in LDS (bf16 Zs[n][t]) and writes Y fp8 directly -- no Z in HBM,
// no separate recurrence kernel. GEMM core keeps the R4/R7-proven structure:
// A+B staged via global_load_lds (XOR-chunk swizzle), 2 barriers per K-tile,
// mfma_scale_f32_16x16x128_f8f6f4 with unit scales, swapped operands.

#define BDIM 256
#define TT   100
#define TP   112         // T padded to 7*16
#define BB   256
#define MM2  (BB * TP)   // 28672 rows
#define NMID 1024
#define K1   784
#define K1P  896         // 784 padded to 7*128
#define NOUT 10
#define N4P  16          // layer-4 N padded
#define L_TAU 0.8f

typedef __attribute__((ext_vector_type(4))) int   int4x;
typedef __attribute__((ext_vector_type(8))) int   int8x;
typedef __attribute__((ext_vector_type(4))) float f32x4;

__device__ __forceinline__ void async_copy16(const void* g, void* l) {
    __builtin_amdgcn_global_load_lds(
        (const __attribute__((address_space(1))) unsigned int*)g,
        (__attribute__((address_space(3))) unsigned int*)l,
        16, 0, 0);
}

__device__ __forceinline__ unsigned short f2bf(float f) {
    __hip_bfloat16 h = __float2bfloat16(f);
    return __builtin_bit_cast(unsigned short, h);
}
__device__ __forceinline__ float bf2f(unsigned short u) {
    return __uint_as_float((unsigned)u << 16);
}

// ---- X f32 [B][T][784] -> fp8 [b*TP+t][896] zero-padded --------------------
__global__ void convert_x(const float* __restrict__ X, unsigned char* __restrict__ XB) {
    int m = blockIdx.x;                  // t*BB + b enumeration (25600 blocks)
    int b = m & (BB - 1);
    int t = m >> 8;
    int th = threadIdx.x;
    if (th >= K1P / 4) return;           // 224 active threads
    int pk = 0;
    if (th < K1 / 4) {                   // 196 threads cover cols 0..783 exactly
        float4 v = *(const float4*)(X + ((long)b * TT + t) * K1 + th * 4);
        pk = __builtin_amdgcn_cvt_pk_fp8_f32(v.x, v.y, 0, false);
        pk = __builtin_amdgcn_cvt_pk_fp8_f32(v.z, v.w, pk, true);
    }
    *(int*)(XB + ((long)b * TP + t) * K1P + th * 4) = pk;
}

// ---- W f32 [K,N] -> WT fp8 [N,Kpad], zero-pad k>=K -------------------------
__device__ __forceinline__ void tc_body(const float* __restrict__ W,
                                        unsigned char* __restrict__ WT,
                                        int K, int N, int Kpad,
                                        int bx, int by, int tidx) {
    __shared__ float tile[32][33];
    int k0 = bx * 32;
    int n0 = by * 32;
    int tx = tidx & 31, ty = tidx >> 5;   // 256 threads: ty=0..7
    #pragma unroll
    for (int i = 0; i < 4; ++i) {
        int k = k0 + ty + i * 8;
        tile[ty + i * 8][tx] = (k < K) ? W[(long)k * N + n0 + tx] : 0.0f;
    }
    __syncthreads();
    int nl = tidx >> 3, kq = tidx & 7;    // n-local 0..31, k-quad 0..7
    int pk = __builtin_amdgcn_cvt_pk_fp8_f32(tile[kq * 4 + 0][nl], tile[kq * 4 + 1][nl], 0, false);
    pk     = __builtin_amdgcn_cvt_pk_fp8_f32(tile[kq * 4 + 2][nl], tile[kq * 4 + 3][nl], pk, true);
    *(int*)(WT + (long)(n0 + nl) * Kpad + k0 + kq * 4) = pk;
}

__global__ void transpose_convert(const float* __restrict__ W, unsigned char* __restrict__ WT,
                                  int K, int N, int Kpad) {
    tc_body(W, WT, K, N, Kpad, blockIdx.x, blockIdx.y, threadIdx.x);
}

__global__ void transpose_convert2(const float* __restrict__ Wa, unsigned char* __restrict__ Ta,
                                   const float* __restrict__ Wb, unsigned char* __restrict__ Tb) {
    const float* W = blockIdx.z ? Wb : Wa;
    unsigned char* T = blockIdx.z ? Tb : Ta;
    tc_body(W, T, NMID, NMID, NMID, blockIdx.x, blockIdx.y, threadIdx.x);
}

// ---- W4 f32 [1024,10] -> fp8 [16][1024], zero-pad n>=10 --------------------
__global__ void convert_w4(const float* __restrict__ W4, unsigned char* __restrict__ W4T) {
    int tid = blockIdx.x * BDIM + threadIdx.x;   // n*256 + k4, 4096 total
    int n = tid >> 8;
    int k4 = (tid & 255) * 4;
    float v0 = 0, v1 = 0, v2 = 0, v3 = 0;
    if (n < NOUT) {
        v0 = W4[(k4 + 0) * NOUT + n];
        v1 = W4[(k4 + 1) * NOUT + n];
        v2 = W4[(k4 + 2) * NOUT + n];
        v3 = W4[(k4 + 3) * NOUT + n];
    }
    int pk = __builtin_amdgcn_cvt_pk_fp8_f32(v0, v1, 0, false);
    pk     = __builtin_amdgcn_cvt_pk_fp8_f32(v2, v3, pk, true);
    *(int*)(W4T + (long)n * NMID + k4) = pk;
}

// ---- Fused GEMM + SNU recurrence -------------------------------------------
// Block = (b, n-block): 112x128 tile over full K. GEMM phase stages A(112x128)
// + B(128x128) per K-tile; 4 waves x 32 cols, 7x2 16x16x128 MFMA frags.
// Epilogue: acc -> Zs bf16 [n][t] in LDS (unioned w/ staging); 128 threads
// run the t-recurrence and write Y fp8 [b*TP+t][NMID].
__global__ __launch_bounds__(256) void gemm_snu_fused(
    const unsigned char* __restrict__ A,    // [MM2, Kp] fp8 (b-major rows)
    const unsigned char* __restrict__ BT,   // [NMID, Kp] fp8
    const float* __restrict__ bias,         // [NMID]
    unsigned char* __restrict__ Y,          // [MM2, NMID] fp8 (b-major rows)
    int Kp)
{
    __shared__ unsigned char smem[30720];
    unsigned char* As = smem;                    // [112][128]
    unsigned char* Bs = smem + 14336;            // [128][128]
    unsigned short* Zs = (unsigned short*)smem;  // [128][114] bf16, n-major

    const int tid  = threadIdx.x;
    const int wave = tid >> 6;
    const int lane = tid & 63;

    // XCD swizzle: 32 b's x 8 n-blocks per XCD -> A strips stay L2-local
    const int l   = blockIdx.x;
    const int xcd = l & 7;
    const int p   = l >> 3;                 // 0..255
    const int b   = xcd * 32 + (p >> 3);
    const int bn  = (p & 7) * 128;

    const long arow0 = (long)b * TP;

    f32x4 acc[7][2] = {};

    const int srow = tid >> 3;              // 0..31
    const int lch  = tid & 7;
    const int gch  = lch ^ (srow & 7);
    const unsigned char* Aptr = A  + (arow0 + srow) * Kp + gch * 16;
    const unsigned char* Bptr = BT + (long)(bn + srow) * Kp + gch * 16;

    const int mrow = lane & 15;
    const int g    = lane >> 4;             // K-group / n-reg group
    const int wc   = wave * 32;             // wave's column offset

    for (int k0 = 0; k0 < Kp; k0 += 128) {
        #pragma unroll
        for (int i = 0; i < 4; ++i) {
            if (srow + i * 32 < TP)          // A: 112 rows (3.5 staging steps)
                async_copy16(Aptr + (long)(i * 32) * Kp + k0,
                             &As[(srow + i * 32) * 128 + lch * 16]);
            async_copy16(Bptr + (long)(i * 32) * Kp + k0,
                         &Bs[(srow + i * 32) * 128 + lch * 16]);
        }
        __syncthreads();

        int8x bfr[2];
        #pragma unroll
        for (int j = 0; j < 2; ++j) {
            int row = wc + j * 16 + mrow;
            int r7  = row & 7;
            int4x lo = *(const int4x*)&Bs[row * 128 + ((2 * g    ) ^ r7) * 16];
            int4x hi = *(const int4x*)&Bs[row * 128 + ((2 * g + 1) ^ r7) * 16];
            bfr[j][0] = lo[0]; bfr[j][1] = lo[1]; bfr[j][2] = lo[2]; bfr[j][3] = lo[3];
            bfr[j][4] = hi[0]; bfr[j][5] = hi[1]; bfr[j][6] = hi[2]; bfr[j][7] = hi[3];
        }
        #pragma unroll
        for (int i = 0; i < 7; ++i) {
            int row = i * 16 + mrow;
            int r7  = row & 7;
            int4x lo = *(const int4x*)&As[row * 128 + ((2 * g    ) ^ r7) * 16];
            int4x hi = *(const int4x*)&As[row * 128 + ((2 * g + 1) ^ r7) * 16];
            int8x af;
            af[0] = lo[0]; af[1] = lo[1]; af[2] = lo[2]; af[3] = lo[3];
            af[4] = hi[0]; af[5] = hi[1]; af[6] = hi[2]; af[7] = hi[3];
            #pragma unroll
            for (int j = 0; j < 2; ++j)
                acc[i][j] = __builtin_amdgcn_mfma_scale_f32_16x16x128_f8f6f4(
                    bfr[j], af, acc[i][j],
                    0, 0,            // cbsz=fp8 e4m3, blgp=fp8 e4m3
                    0, 0x7F,         // unit scale
                    0, 0x7F);
        }
        __syncthreads();
    }

    // epilogue: acc (lane&15 -> t-in-tile, g*4+reg -> n-in-16) -> Zs[n][t] bf16
    #pragma unroll
    for (int i = 0; i < 7; ++i)
        #pragma unroll
        for (int j = 0; j < 2; ++j) {
            int t  = i * 16 + mrow;
            int nn = wc + j * 16 + g * 4;
            #pragma unroll
            for (int r = 0; r < 4; ++r)
                Zs[(nn + r) * 114 + t] = f2bf(acc[i][j][r]);
        }
    __syncthreads();

    // recurrence: thread n of 128 walks t sequentially, writes Y fp8
    if (tid < 128) {
        int n = tid;
        float bv = bias[bn + n];
        float s = 0.0f, yv = 0.0f;
        const unsigned short* zp = Zs + n * 114;
        unsigned char* yp = Y + arow0 * NMID + bn + n;
        for (int t = 0; t < TT; ++t) {
            float z = bf2f(zp[t]);
            s = fmaxf(fmaf(L_TAU * s, 1.0f - yv, z), 0.0f);
            yv = 1.0f / (1.0f + __expf(-(s + bv)));
            int pk = __builtin_amdgcn_cvt_pk_fp8_f32(yv, yv, 0, false);
            yp[(long)t * NMID] = (unsigned char)(pk & 0xFF);
        }
    }
}

// ---- Layer 4 GEMM: Z4[MM2,16] = Y3[MM2,1024](fp8) * W4T[16,1024]^T ---------
__global__ __launch_bounds__(256) void layer4_gemm(const unsigned char* __restrict__ Y3,
                                                   const unsigned char* __restrict__ W4T,
                                                   float* __restrict__ Z4) {
    const int tid  = threadIdx.x;
    const int wave = tid >> 6;
    const int lane = tid & 63;
    const int mrow = lane & 15;
    const int g    = lane >> 4;
    const int row  = blockIdx.x * 64 + wave * 16 + mrow;
    const unsigned char* ap = Y3  + (long)row  * NMID + g * 32;
    const unsigned char* wp = W4T + (long)mrow * NMID + g * 32;
    f32x4 acc = {};
    #pragma unroll
    for (int kt = 0; kt < 8; ++kt) {
        int4x alo = *(const int4x*)(ap + kt * 128);
        int4x ahi = *(const int4x*)(ap + kt * 128 + 16);
        int4x wlo = *(const int4x*)(wp + kt * 128);
        int4x whi = *(const int4x*)(wp + kt * 128 + 16);
        int8x af, bf;
        af[0] = alo[0]; af[1] = alo[1]; af[2] = alo[2]; af[3] = alo[3];
        af[4] = ahi[0]; af[5] = ahi[1]; af[6] = ahi[2]; af[7] = ahi[3];
        bf[0] = wlo[0]; bf[1] = wlo[1]; bf[2] = wlo[2]; bf[3] = wlo[3];
        bf[4] = whi[0]; bf[5] = whi[1]; bf[6] = whi[2]; bf[7] = whi[3];
        acc = __builtin_amdgcn_mfma_scale_f32_16x16x128_f8f6f4(
            bf, af, acc, 0, 0, 0, 0x7F, 0, 0x7F);
    }
    *(f32x4*)&Z4[(long)row * N4P + g * 4] = acc;
}

// ---- Layer 4 recurrence + m accumulation (Z4 [b*TP+t][16] f32) -------------
__global__ void snu4_recur(const float* __restrict__ Z4, const float* __restrict__ b4,
                           float* __restrict__ m_out) {
    int idx = blockIdx.x * BDIM + threadIdx.x;   // b*16+n, 4096 total
    int n = idx & 15;
    int b = idx >> 4;
    if (n >= NOUT) return;
    float bv = b4[n];
    float s = 0.0f, y = 0.0f, msum = 0.0f;
    const float* zp = Z4 + (long)b * TP * N4P + n;
    for (int t0 = 0; t0 < TT; t0 += 4) {
        float z[4];
        #pragma unroll
        for (int j = 0; j < 4; ++j)
            z[j] = zp[(t0 + j) * N4P];
        #pragma unroll
        for (int j = 0; j < 4; ++j) {
            s = fmaxf(fmaf(L_TAU * s, 1.0f - y, z[j]), 0.0f);
            y = 1.0f / (1.0f + __expf(-(s + bv)));
            msum += y;
        }
    }
    m_out[b * NOUT + n] = msum;
}

// ---- loss = -mean_b log_softmax(m)[b, y[b]] --------------------------------
__global__ void loss_kernel(const float* __restrict__ m, const int* __restrict__ y,
                            float* __restrict__ out) {
    __shared__ float red[BDIM];
    int b = threadIdx.x;   // 256 threads, 1 block
    float v[NOUT];
    float mx = -1e30f;
    #pragma unroll
    for (int n = 0; n < NOUT; ++n) { v[n] = m[b * NOUT + n]; mx = fmaxf(mx, v[n]); }
    float se = 0.0f;
    #pragma unroll
    for (int n = 0; n < NOUT; ++n) se += __expf(v[n] - mx);
    float lse = mx + __logf(se);
    int lbl = y[b];
    float vy = 0.0f;
    #pragma unroll
    for (int n = 0; n < NOUT; ++n) if (n == lbl) vy = v[n];
    red[b] = -(vy - lse);
    __syncthreads();
    for (int off = 128; off; off >>= 1) {
        if (b < off) red[b] += red[b + off];
        __syncthreads();
    }
    if (b == 0) out[0] = red[0] / (float)BB;
}

extern "C" void kernel_launch(void* const* d_in, const int* in_sizes, int n_in,
                              void* d_out, int out_size, void* d_ws, size_t ws_size,
                              hipStream_t stream) {
    const float* x  = (const float*)d_in[0];
    const int*   y  = (const int*)  d_in[1];
    const float* W1 = (const float*)d_in[2];
    const float* b1 = (const float*)d_in[3];
    const float* W2 = (const float*)d_in[4];
    const float* b2 = (const float*)d_in[5];
    const float* W3 = (const float*)d_in[6];
    const float* b3 = (const float*)d_in[7];
    const float* W4 = (const float*)d_in[8];
    const float* b4 = (const float*)d_in[9];
    float* out = (float*)d_out;

    char* ws = (char*)d_ws;
    size_t off = 0;
    auto alloc = [&](size_t bytes) {
        char* p = ws + off;
        off = (off + bytes + 255) & ~(size_t)255;
        return (void*)p;
    };
    unsigned char* XB  = (unsigned char*)alloc((size_t)MM2 * K1P);
    unsigned char* W1T = (unsigned char*)alloc((size_t)NMID * K1P);
    unsigned char* W2T = (unsigned char*)alloc((size_t)NMID * NMID);
    unsigned char* W3T = (unsigned char*)alloc((size_t)NMID * NMID);
    unsigned char* W4T = (unsigned char*)alloc((size_t)N4P * NMID);
    unsigned char* Ya  = (unsigned char*)alloc((size_t)MM2 * NMID);
    unsigned char* Yb  = (unsigned char*)alloc((size_t)MM2 * NMID);
    float*         Z4  = (float*)        alloc((size_t)MM2 * N4P * 4);

    // prep
    convert_x<<<BB * TT, BDIM, 0, stream>>>(x, XB);
    transpose_convert<<<dim3(K1P / 32, NMID / 32), BDIM, 0, stream>>>(W1, W1T, K1, NMID, K1P);
    transpose_convert2<<<dim3(NMID / 32, NMID / 32, 2), BDIM, 0, stream>>>(W2, W2T, W3, W3T);
    convert_w4<<<N4P * NMID / 4 / BDIM, BDIM, 0, stream>>>(W4, W4T);

    const int fblocks = BB * (NMID / 128);   // 2048
    gemm_snu_fused<<<fblocks, BDIM, 0, stream>>>(XB, W1T, b1, Ya, K1P);
    gemm_snu_fused<<<fblocks, BDIM, 0, stream>>>(Ya, W2T, b2, Yb, NMID);
    gemm_snu_fused<<<fblocks, BDIM, 0, stream>>>(Yb, W3T, b3, Ya, NMID);
    layer4_gemm<<<MM2 / 64, BDIM, 0, stream>>>(Ya, W4T, Z4);
    snu4_recur<<<(BB * N4P) / BDIM, BDIM, 0, stream>>>(Z4, b4, out + 1);
    loss_kernel<<<1, BDIM, 0, stream>>>(out + 1, y, out);
}